// Round 5
// baseline (328.623 us; speedup 1.0000x reference)
//
#include <hip/hip_runtime.h>
#include <hip/hip_bf16.h>
#include <cfloat>

// VQ-VAE vector quantizer.  N=262144 rows x D=100, K=512 codes.
// out[0..N*D-1] = quantized (fp32-exact gather); out[N*D]=mse; out[N*D+1]=0.25*mse.
//
// R10: swarm of barrier-free single-wave workgroups.
//  Post-mortem R5-R9: dur pinned 104-132us across {16 bar,0 bar}x{LDS B,L2 B}x
//  {4-wave,8-wave blocks}.  Invariant: resident waves/CU ~ 6.5-7.5 in EVERY
//  config (even when resources allow 16-32) => suspect the scheduler co-resides
//  only ~2 workgroups/CU, making waves/CU = 2 x waves/block.  Single-wave
//  blocks are the finest granule: if the theory holds, 16 blocks/CU co-reside
//  (VGPR<=128 via launch_bounds(64,4)) and latency finally hides via TLP.
//   - 64-thread blocks, M=2 (32 rows/block), grid 8192, ZERO __syncthreads
//   - B direct from L2-resident 128KB cb granule table; depth-1 register
//     ping-pong prefetch at half-chunk (tt) granularity; e2 scalar from L2
//   - per-block epilogue via 128B LDS widx (same-wave lgkmcnt only)
//   - math / chunk order / tie-break bitwise-identical to R5-R9
//  Tripwires: VGPR 100-128 (NOT 64); WRITE_SIZE exactly 102416; conflicts 0.
//  Falsifier: dur>=95us & occ ~20% => co-scheduling not the limiter; pivot to
//  within-wave ILP (prefetch depth 2-3).
//
// ws: ws_f[2w], w=0..7 = loss accum slots; ws_f[16..528) = e2[k] (fp32);
//     bytes [4096..4096+131072): bf16 cb; chunk c granule layout (16B granules):
//     granule g = (s*2+tt)*64 + quad*16 + lr  holds code (c*32+tt*16+lr),
//     k = s*32+quad*8+{0..7}  (zero-padded for k>=100).

#define N_ROWS (64 * 64 * 64)
#define D 100
#define KCODES 512
#define CB_OFF 4096
#define E2_OFF 16

typedef __attribute__((ext_vector_type(8))) short short8;
typedef __attribute__((ext_vector_type(4))) float f32x4;

__device__ __forceinline__ unsigned short f2bf(float f) {
    union { float f; unsigned u; } v; v.f = f;
    unsigned r = v.u + 0x7FFF + ((v.u >> 16) & 1);   // RNE
    return (unsigned short)(r >> 16);
}
__device__ __forceinline__ unsigned pk2(float a, float b) {   // packed bf16 cvt (RNE)
    union { __hip_bfloat162 h; unsigned u; } c;
    c.h = __float22bfloat162_rn(make_float2(a, b));
    return c.u;
}
__device__ __forceinline__ short8 pack8(const float4& a, const float4& b) {
    union { unsigned u[4]; short8 v; } r;
    r.u[0] = pk2(a.x, a.y); r.u[1] = pk2(a.z, a.w);
    r.u[2] = pk2(b.x, b.y); r.u[3] = pk2(b.z, b.w);
    return r.v;
}

// ---- init: one wave per code ----
__global__ __launch_bounds__(64) void vq_init(const float* __restrict__ emb,
                                              float* __restrict__ ws) {
    const int code = blockIdx.x, l = threadIdx.x;
    const float* e = emb + code * D;
    if (code == 0 && l < 16) ws[l] = 0.0f;         // loss accum slots (even idx used)
    float a = e[l];
    float b = (l < D - 64) ? e[64 + l] : 0.0f;
    float p = fmaf(a, a, b * b);
#pragma unroll
    for (int off = 32; off; off >>= 1) p += __shfl_xor(p, off);
    if (l == 0) ws[E2_OFF + code] = p;

    // cb granules: 16 per code, written by lanes 0..15 (8 shorts each)
    if (l < 16) {
        const int s = l >> 2, q = l & 3;
        short8 v;
#pragma unroll
        for (int j = 0; j < 8; ++j) {
            int k = s * 32 + q * 8 + j;
            v[j] = (k < D) ? (short)f2bf(e[k]) : (short)0;
        }
        const int chunk = code >> 5, ci = code & 31;
        const int tt = ci >> 4, lr = ci & 15;
        unsigned short* cb = (unsigned short*)((char*)ws + CB_OFF);
        // short offset = chunk*4096 + granule*8, granule = (s*2+tt)*64 + q*16 + lr
        *(short8*)(cb + chunk * 4096 + ((s * 2 + tt) * 64 + q * 16 + lr) * 8) = v;
    }
}

// ---- main: single-wave blocks, 32 rows/block (M=2), B from L2, no barriers ----
__global__ __launch_bounds__(64, 4) void vq_main(const float* __restrict__ x,
                                                 const float* __restrict__ emb,
                                                 float* __restrict__ ws,
                                                 float* __restrict__ out) {
    __shared__ int widx[32];          // 128 B, same-wave use only

    const int lane = threadIdx.x;
    const int quad = lane >> 4, lr = lane & 15;
    const long brow = (long)blockIdx.x * 32;

    // ---- A: 14 independent scattered loads (batched), then convert ----
    float4 av[2][7];
#pragma unroll
    for (int m = 0; m < 2; ++m) {
        const float* xr = x + (brow + m * 16 + lr) * D + quad * 8;
        av[m][0] = *(const float4*)(xr);
        av[m][1] = *(const float4*)(xr + 4);
        av[m][2] = *(const float4*)(xr + 32);
        av[m][3] = *(const float4*)(xr + 36);
        av[m][4] = *(const float4*)(xr + 64);
        av[m][5] = *(const float4*)(xr + 68);
        av[m][6] = *(const float4*)(x + (brow + m * 16 + lr) * D + 96);  // same addr all quads
    }

    // ---- convert A -> fragments + fp32 norms ----
    short8 A[2][4];
    float  xnorm[2];
#pragma unroll
    for (int m = 0; m < 2; ++m) {
        float4 z = av[m][6];
        if (quad != 0) z = make_float4(0.f, 0.f, 0.f, 0.f);   // tail only in quad 0
        float nrm = 0.f;
#pragma unroll
        for (int i = 0; i < 6; ++i) {
            float4 f = av[m][i];
            nrm = fmaf(f.x, f.x, nrm); nrm = fmaf(f.y, f.y, nrm);
            nrm = fmaf(f.z, f.z, nrm); nrm = fmaf(f.w, f.w, nrm);
        }
        nrm = fmaf(z.x, z.x, nrm); nrm = fmaf(z.y, z.y, nrm);
        nrm = fmaf(z.z, z.z, nrm); nrm = fmaf(z.w, z.w, nrm);
        A[m][0] = pack8(av[m][0], av[m][1]);
        A[m][1] = pack8(av[m][2], av[m][3]);
        A[m][2] = pack8(av[m][4], av[m][5]);
        A[m][3] = pack8(z, make_float4(0.f, 0.f, 0.f, 0.f));
        nrm += __shfl_xor(nrm, 16);
        nrm += __shfl_xor(nrm, 32);
        xnorm[m] = nrm;
    }

    const short8* __restrict__ cbg8 = (const short8*)((const char*)ws + CB_OFF);
    const float*  __restrict__ e2g  = ws + E2_OFF;

    float    runmin[2][4];
    unsigned runidx[2][4];
#pragma unroll
    for (int m = 0; m < 2; ++m)
#pragma unroll
        for (int r = 0; r < 4; ++r) { runmin[m][r] = FLT_MAX; runidx[m][r] = 0; }

    // half-chunk hc = c*2 + tt, hc = 0..31; depth-1 register ping-pong prefetch
    short8 B0[4], B1[4];
    float  e20, e21;

#define LOADH(Bv, e2v, hc2)                                                   \
    do {                                                                      \
        const int c_ = (hc2) >> 1, t_ = (hc2) & 1;                            \
        _Pragma("unroll")                                                     \
        for (int s_ = 0; s_ < 4; ++s_)                                        \
            Bv[s_] = cbg8[c_ * 512 + (s_ * 2 + t_) * 64 + lane];              \
        e2v = e2g[c_ * 32 + t_ * 16 + lr];                                    \
    } while (0)

#define COMPH(Bv, e2v, hc2)                                                   \
    do {                                                                      \
        const int c_ = (hc2) >> 1, t_ = (hc2) & 1;                            \
        f32x4 acc_[2];                                                        \
        acc_[0] = (f32x4){0.f, 0.f, 0.f, 0.f};                                \
        acc_[1] = (f32x4){0.f, 0.f, 0.f, 0.f};                                \
        _Pragma("unroll")                                                     \
        for (int s_ = 0; s_ < 4; ++s_) {                                      \
            acc_[0] = __builtin_amdgcn_mfma_f32_16x16x32_bf16(A[0][s_], Bv[s_], acc_[0], 0, 0, 0); \
            acc_[1] = __builtin_amdgcn_mfma_f32_16x16x32_bf16(A[1][s_], Bv[s_], acc_[1], 0, 0, 0); \
        }                                                                     \
        const unsigned code_ = c_ * 32 + t_ * 16 + lr;                        \
        _Pragma("unroll")                                                     \
        for (int m_ = 0; m_ < 2; ++m_)                                        \
            _Pragma("unroll")                                                 \
            for (int r_ = 0; r_ < 4; ++r_) {                                  \
                float sc_ = fmaf(-2.0f, acc_[m_][r_], e2v);                   \
                if (sc_ < runmin[m_][r_]) { runmin[m_][r_] = sc_; runidx[m_][r_] = code_; } \
            }                                                                 \
    } while (0)

    LOADH(B0, e20, 0);
#pragma unroll 1
    for (int hc = 0; hc < 32; hc += 2) {
        LOADH(B1, e21, hc + 1);
        COMPH(B0, e20, hc);
        if (hc < 30) LOADH(B0, e20, hc + 2);
        COMPH(B1, e21, hc + 1);
    }
#undef LOADH
#undef COMPH

    // ---- per-row argmin across the 16 columns (xor 8,4,2,1 stays in quad) ----
    float lsum = 0.0f;
#pragma unroll
    for (int m = 0; m < 2; ++m)
#pragma unroll
        for (int r = 0; r < 4; ++r) {
            float    s = runmin[m][r];
            unsigned i = runidx[m][r];
#pragma unroll
            for (int off = 8; off >= 1; off >>= 1) {
                float    os = __shfl_xor(s, off);
                unsigned oi = (unsigned)__shfl_xor((int)i, off);
                if (os < s || (os == s && oi < i)) { s = os; i = oi; }
            }
            if (lr == quad * 4 + r) {                  // writer lane for this row
                lsum += xnorm[m] + s;                  // ||x||^2 + e2 - 2<x,e>
                widx[m * 16 + quad * 4 + r] = (int)i;
            }
        }
#pragma unroll
    for (int off = 32; off >= 1; off >>= 1) lsum += __shfl_xor(lsum, off);
    if (lane == 0) atomicAdd(&ws[(blockIdx.x & 7) * 2], lsum);   // 8 spread slots

    // same-wave LDS visibility (no block barrier needed)
    asm volatile("s_waitcnt lgkmcnt(0)" ::: "memory");

    // ---- coalesced epilogue: 800 float4 = 32 rows x 25, batched 4-deep ----
    const float4* __restrict__ ef = (const float4*)emb;   // 25 float4 per row, exact
    float4* __restrict__ og = (float4*)(out + brow * D);
#pragma unroll
    for (int i = 0; i < 16; i += 4) {
        float4 q[4];
        int    gi[4];
        bool   ok[4];
#pragma unroll
        for (int u = 0; u < 4; ++u) {
            int g = (i + u) * 64 + lane;
            ok[u] = (g < 800);
            int row = g / 25;                 // const-divisor magic div
            int c4  = g - row * 25;
            gi[u] = g;
            if (ok[u]) q[u] = ef[(long)widx[row] * 25 + c4];
        }
#pragma unroll
        for (int u = 0; u < 4; ++u)
            if (ok[u]) og[gi[u]] = q[u];
    }
}

// ---- finalize ----
__global__ void vq_final(const float* __restrict__ ws, float* __restrict__ out) {
    float t = 0.f;
#pragma unroll
    for (int w = 0; w < 8; ++w) t += ws[w * 2];
    float mse = t / (float)((long)N_ROWS * D);
    out[(long)N_ROWS * D]     = mse;
    out[(long)N_ROWS * D + 1] = 0.25f * mse;
}

extern "C" void kernel_launch(void* const* d_in, const int* in_sizes, int n_in,
                              void* d_out, int out_size, void* d_ws, size_t ws_size,
                              hipStream_t stream) {
    const float* x   = (const float*)d_in[0];
    const float* emb = (const float*)d_in[1];
    float* out = (float*)d_out;
    float* ws  = (float*)d_ws;

    vq_init<<<KCODES, 64, 0, stream>>>(emb, ws);
    vq_main<<<N_ROWS / 32, 64, 0, stream>>>(x, emb, ws, out);
    vq_final<<<1, 1, 0, stream>>>(ws, out);
}

// Round 6
// 226.872 us; speedup vs baseline: 1.4485x; 1.4485x over previous
//
#include <hip/hip_runtime.h>
#include <hip/hip_bf16.h>
#include <cfloat>

// VQ-VAE vector quantizer.  N=262144 rows x D=100, K=512 codes.
// out[0..N*D-1] = quantized (fp32-exact gather); out[N*D]=mse; out[N*D+1]=0.25*mse.
//
// R11: R5 (best-known, 104us) with 2-chunk staging rounds (8 barriers).
//  Scoreboard R5-R10: every structural departure from R5 regressed
//  (R6 L2/0-bar 114, R8 8-wave 110, R9 all-LDS/0-bar 132, R10 1-wave swarm 207).
//  R11 returns to R5 byte-for-byte and changes ONE thing: staging granularity
//  2 chunks/round -> 16 KB double buffers, 8 barriers instead of 16.
//   - halves the per-round {vmcnt(0) drain -> ds_write -> __syncthreads} events
//   - each staging round's L2 prefetch is covered by ~2.2K cycles of compute
//     (2 chunks of MFMA+fold) instead of ~1.1K
//   - math order, fold, granule layout, epilogue: bit-identical to R5
//  Cost: LDS 20->36 KB (still 4 blocks/CU), +16 VGPR for 4-deep prefetch.
//  Tripwires: VGPR 95-110 (NOT 64, no spill); WRITE exactly 102432; conflicts 0.
//  Falsifier: dur 100-110 => barrier/drain theory dead -> next round is the
//  chunk-recompute (idempotent) bisect of main-loop vs prologue/epilogue.
//
// ws: ws_f[0] = loss accum; ws_f[16..528) = e2[k] (fp32);
//     bytes [4096..4096+131072): bf16 cb; chunk c granule layout (16B granules):
//     granule g = (s*2+tt)*64 + quad*16 + lr  holds code (c*32+tt*16+lr),
//     k = s*32+quad*8+{0..7}  (zero-padded for k>=100).

#define N_ROWS (64 * 64 * 64)
#define D 100
#define KCODES 512
#define CB_OFF 4096
#define E2_OFF 16

typedef __attribute__((ext_vector_type(8))) short short8;
typedef __attribute__((ext_vector_type(4))) float f32x4;

__device__ __forceinline__ unsigned short f2bf(float f) {
    union { float f; unsigned u; } v; v.f = f;
    unsigned r = v.u + 0x7FFF + ((v.u >> 16) & 1);   // RNE
    return (unsigned short)(r >> 16);
}
__device__ __forceinline__ unsigned pk2(float a, float b) {   // packed bf16 cvt (RNE)
    union { __hip_bfloat162 h; unsigned u; } c;
    c.h = __float22bfloat162_rn(make_float2(a, b));
    return c.u;
}
__device__ __forceinline__ short8 pack8(const float4& a, const float4& b) {
    union { unsigned u[4]; short8 v; } r;
    r.u[0] = pk2(a.x, a.y); r.u[1] = pk2(a.z, a.w);
    r.u[2] = pk2(b.x, b.y); r.u[3] = pk2(b.z, b.w);
    return r.v;
}

// ---- init: one wave per code ----
__global__ __launch_bounds__(64) void vq_init(const float* __restrict__ emb,
                                              float* __restrict__ ws) {
    const int code = blockIdx.x, l = threadIdx.x;
    const float* e = emb + code * D;
    if (code == 0 && l == 0) ws[0] = 0.0f;
    float a = e[l];
    float b = (l < D - 64) ? e[64 + l] : 0.0f;
    float p = fmaf(a, a, b * b);
#pragma unroll
    for (int off = 32; off; off >>= 1) p += __shfl_xor(p, off);
    if (l == 0) ws[E2_OFF + code] = p;

    // cb granules: 16 per code, written by lanes 0..15 (8 shorts each)
    if (l < 16) {
        const int s = l >> 2, q = l & 3;
        short8 v;
#pragma unroll
        for (int j = 0; j < 8; ++j) {
            int k = s * 32 + q * 8 + j;
            v[j] = (k < D) ? (short)f2bf(e[k]) : (short)0;
        }
        const int chunk = code >> 5, ci = code & 31;
        const int tt = ci >> 4, lr = ci & 15;
        unsigned short* cb = (unsigned short*)((char*)ws + CB_OFF);
        // short offset = chunk*4096 + granule*8, granule = (s*2+tt)*64 + q*16 + lr
        *(short8*)(cb + chunk * 4096 + ((s * 2 + tt) * 64 + q * 16 + lr) * 8) = v;
    }
}

// ---- main: 4 waves/block, 64 rows/wave (M=4), B via 2-chunk double-buffered LDS ----
__global__ __launch_bounds__(256, 2) void vq_main(const float* __restrict__ x,
                                                  const float* __restrict__ emb,
                                                  float* __restrict__ ws,
                                                  float* __restrict__ out) {
    __shared__ uint4  bbuf[2][1024];  // 2 x 16 KB: two chunks per buffer
    __shared__ float  e2s[KCODES];    // 2 KB
    __shared__ int    widx[256];
    __shared__ float  wsum[4];

    const int tid = threadIdx.x, wave = tid >> 6, lane = tid & 63;
    const int quad = lane >> 4, lr = lane & 15;
    const long brow = (long)blockIdx.x * 256;
    const long wrow = brow + wave * 64;

    // ---- A: 28 independent scattered loads (batched), then convert ----
    float4 av[4][7];
#pragma unroll
    for (int m = 0; m < 4; ++m) {
        const float* xr = x + (wrow + m * 16 + lr) * D + quad * 8;
        av[m][0] = *(const float4*)(xr);
        av[m][1] = *(const float4*)(xr + 4);
        av[m][2] = *(const float4*)(xr + 32);
        av[m][3] = *(const float4*)(xr + 36);
        av[m][4] = *(const float4*)(xr + 64);
        av[m][5] = *(const float4*)(xr + 68);
        av[m][6] = *(const float4*)(x + (wrow + m * 16 + lr) * D + 96);  // same addr all quads
    }

    // ---- B chunks 0,1 + e2 staging (issued while A loads are in flight) ----
    const uint4* __restrict__ cbg = (const uint4*)((const char*)ws + CB_OFF);
    uint4 st0 = cbg[wave * 128 + lane];
    uint4 st1 = cbg[wave * 128 + 64 + lane];
    uint4 st2 = cbg[512 + wave * 128 + lane];
    uint4 st3 = cbg[512 + wave * 128 + 64 + lane];
    const float* __restrict__ e2g = ws + E2_OFF;
    e2s[tid]       = e2g[tid];
    e2s[256 + tid] = e2g[256 + tid];

    // ---- convert A -> fragments + fp32 norms ----
    short8 A[4][4];
    float  xnorm[4];
#pragma unroll
    for (int m = 0; m < 4; ++m) {
        float4 z = av[m][6];
        if (quad != 0) z = make_float4(0.f, 0.f, 0.f, 0.f);   // tail only in quad 0
        float nrm = 0.f;
#pragma unroll
        for (int i = 0; i < 6; ++i) {
            float4 f = av[m][i];
            nrm = fmaf(f.x, f.x, nrm); nrm = fmaf(f.y, f.y, nrm);
            nrm = fmaf(f.z, f.z, nrm); nrm = fmaf(f.w, f.w, nrm);
        }
        nrm = fmaf(z.x, z.x, nrm); nrm = fmaf(z.y, z.y, nrm);
        nrm = fmaf(z.z, z.z, nrm); nrm = fmaf(z.w, z.w, nrm);
        A[m][0] = pack8(av[m][0], av[m][1]);
        A[m][1] = pack8(av[m][2], av[m][3]);
        A[m][2] = pack8(av[m][4], av[m][5]);
        A[m][3] = pack8(z, make_float4(0.f, 0.f, 0.f, 0.f));
        nrm += __shfl_xor(nrm, 16);
        nrm += __shfl_xor(nrm, 32);
        xnorm[m] = nrm;
    }

    bbuf[0][wave * 128 + lane]             = st0;
    bbuf[0][wave * 128 + 64 + lane]        = st1;
    bbuf[0][512 + wave * 128 + lane]       = st2;
    bbuf[0][512 + wave * 128 + 64 + lane]  = st3;
    __syncthreads();

    float    runmin[4][4];
    unsigned runidx[4][4];
#pragma unroll
    for (int m = 0; m < 4; ++m)
#pragma unroll
        for (int r = 0; r < 4; ++r) { runmin[m][r] = FLT_MAX; runidx[m][r] = 0; }

#pragma unroll 1
    for (int j = 0; j < 8; ++j) {
        const int p = j & 1;
        uint4 n0, n1, n2, n3;
        if (j < 7) {                      // prefetch next 2 chunks into regs
            n0 = cbg[(j + 1) * 1024 + wave * 128 + lane];
            n1 = cbg[(j + 1) * 1024 + wave * 128 + 64 + lane];
            n2 = cbg[(j + 1) * 1024 + 512 + wave * 128 + lane];
            n3 = cbg[(j + 1) * 1024 + 512 + wave * 128 + 64 + lane];
        }

#pragma unroll
        for (int cc = 0; cc < 2; ++cc) {
            const int c = j * 2 + cc;
            // B fragments: lane-linear ds_read_b128, conflict-free
            const short8* __restrict__ bl = (const short8*)&bbuf[p][cc * 512];
            short8 B[2][4];
#pragma unroll
            for (int s = 0; s < 4; ++s) {
                B[0][s] = bl[(s * 2 + 0) * 64 + lane];
                B[1][s] = bl[(s * 2 + 1) * 64 + lane];
            }
            float e2v0 = e2s[c * 32 + lr];
            float e2v1 = e2s[c * 32 + 16 + lr];

            f32x4 acc[4][2];
#pragma unroll
            for (int m = 0; m < 4; ++m) {
                acc[m][0] = (f32x4){0.f, 0.f, 0.f, 0.f};
                acc[m][1] = (f32x4){0.f, 0.f, 0.f, 0.f};
            }
#pragma unroll
            for (int s = 0; s < 4; ++s)
#pragma unroll
                for (int m = 0; m < 4; ++m) {
                    acc[m][0] = __builtin_amdgcn_mfma_f32_16x16x32_bf16(A[m][s], B[0][s], acc[m][0], 0, 0, 0);
                    acc[m][1] = __builtin_amdgcn_mfma_f32_16x16x32_bf16(A[m][s], B[1][s], acc[m][1], 0, 0, 0);
                }

            // fold: score = e2 - 2<x,e>; C layout row=quad*4+r, col=lr
#pragma unroll
            for (int m = 0; m < 4; ++m)
#pragma unroll
                for (int tt = 0; tt < 2; ++tt) {
                    float e2v = tt ? e2v1 : e2v0;
                    unsigned code = c * 32 + tt * 16 + lr;
#pragma unroll
                    for (int r = 0; r < 4; ++r) {
                        float sc = fmaf(-2.0f, acc[m][tt][r], e2v);
                        if (sc < runmin[m][r]) { runmin[m][r] = sc; runidx[m][r] = code; }
                    }
                }
        }

        if (j < 7) {
            bbuf[p ^ 1][wave * 128 + lane]            = n0;
            bbuf[p ^ 1][wave * 128 + 64 + lane]       = n1;
            bbuf[p ^ 1][512 + wave * 128 + lane]      = n2;
            bbuf[p ^ 1][512 + wave * 128 + 64 + lane] = n3;
        }
        __syncthreads();
    }

    // ---- per-row argmin across the 16 columns (xor 8,4,2,1 stays in quad) ----
    float lsum = 0.0f;
#pragma unroll
    for (int m = 0; m < 4; ++m)
#pragma unroll
        for (int r = 0; r < 4; ++r) {
            float    s = runmin[m][r];
            unsigned i = runidx[m][r];
#pragma unroll
            for (int off = 8; off >= 1; off >>= 1) {
                float    os = __shfl_xor(s, off);
                unsigned oi = (unsigned)__shfl_xor((int)i, off);
                if (os < s || (os == s && oi < i)) { s = os; i = oi; }
            }
            if (lr == quad * 4 + r) {                  // writer lane for this row
                lsum += xnorm[m] + s;                  // ||x||^2 + e2 - 2<x,e>
                widx[wave * 64 + m * 16 + quad * 4 + r] = (int)i;
            }
        }
#pragma unroll
    for (int off = 32; off >= 1; off >>= 1) lsum += __shfl_xor(lsum, off);
    if (lane == 0) wsum[wave] = lsum;
    __syncthreads();                                   // wsum + widx visible
    if (tid == 0) atomicAdd(ws, wsum[0] + wsum[1] + wsum[2] + wsum[3]);

    // ---- coalesced epilogue: 6400 float4 = 256 rows x 25, batched 5-deep ----
    const float4* __restrict__ ef = (const float4*)emb;   // 25 float4 per row, exact
    float4* __restrict__ og = (float4*)(out + brow * D);
#pragma unroll
    for (int i = 0; i < 25; i += 5) {
        float4 q[5];
        int    gi[5];
#pragma unroll
        for (int u = 0; u < 5; ++u) {
            int g = (i + u) * 256 + tid;
            int row = g / 25;                 // const-divisor magic div
            int c4  = g - row * 25;
            gi[u] = g;
            q[u]  = ef[(long)widx[row] * 25 + c4];
        }
#pragma unroll
        for (int u = 0; u < 5; ++u) og[gi[u]] = q[u];
    }
}

// ---- finalize ----
__global__ void vq_final(const float* __restrict__ ws, float* __restrict__ out) {
    float mse = ws[0] / (float)((long)N_ROWS * D);
    out[(long)N_ROWS * D]     = mse;
    out[(long)N_ROWS * D + 1] = 0.25f * mse;
}

extern "C" void kernel_launch(void* const* d_in, const int* in_sizes, int n_in,
                              void* d_out, int out_size, void* d_ws, size_t ws_size,
                              hipStream_t stream) {
    const float* x   = (const float*)d_in[0];
    const float* emb = (const float*)d_in[1];
    float* out = (float*)d_out;
    float* ws  = (float*)d_ws;

    vq_init<<<KCODES, 64, 0, stream>>>(emb, ws);
    vq_main<<<N_ROWS / 256, 256, 0, stream>>>(x, emb, ws, out);
    vq_final<<<1, 1, 0, stream>>>(ws, out);
}